// Round 7
// baseline (213.899 us; speedup 1.0000x reference)
//
#include <hip/hip_runtime.h>
#include <hip/hip_bf16.h>

// cos(2*pi*t/8), t = 0..7
__device__ const float C8[8] = {
    1.0f, 0.70710678118654752f, 0.0f, -0.70710678118654752f,
   -1.0f, -0.70710678118654752f, 0.0f, 0.70710678118654752f
};

// Unique-id map for the 8x8 circular-conv kernel, which is even in both axes
// and symmetric under (dy,dx) swap: 15 unique values for d1<=d2 in [0,4].
__host__ __device__ constexpr int kid(int dy, int dx) {
    int a = (dy < 8 - dy) ? dy : 8 - dy;
    int b = (dx < 8 - dx) ? dx : 8 - dx;
    int lo = a < b ? a : b, hi = a < b ? b : a;
    return lo * 5 - lo * (lo - 1) / 2 + (hi - lo);
}

// ---------------- channel mean: x(4,32,512,512) -> xm(4,512,512) ----------------
__global__ __launch_bounds__(256) void k_mean(const float* __restrict__ x,
                                              float* __restrict__ xm) {
    int idx = blockIdx.x * 256 + threadIdx.x;   // float4 index, 262144 total
    int b = idx >> 16;                          // 65536 float4 per batch plane
    int rem = idx & 65535;
    const float4* xp = (const float4*)x + (size_t)b * 32 * 65536 + rem;
    float4 acc = {0.f, 0.f, 0.f, 0.f};
    #pragma unroll 8
    for (int c = 0; c < 32; ++c) {
        float4 v = xp[(size_t)c * 65536];
        acc.x += v.x; acc.y += v.y; acc.z += v.z; acc.w += v.w;
    }
    const float s = 1.0f / 32.0f;
    acc.x *= s; acc.y *= s; acc.z *= s; acc.w *= s;
    ((float4*)xm)[idx] = acc;
}

// ---------------- edge strength per patch: xm -> es(4,64,64) ----------------
__global__ __launch_bounds__(256) void k_edge(const float* __restrict__ xm,
                                              float* __restrict__ es) {
    int b = blockIdx.x >> 6;
    int hti = blockIdx.x & 63;
    int t = threadIdx.x;
    int w = t & 63;     // patch column
    int q = t >> 6;     // quarter: rows q*2, q*2+1 of the patch
    const float* base = xm + (size_t)b * 512 * 512;
    float partial = 0.0f;
    for (int ry = 0; ry < 2; ++ry) {
        int y = hti * 8 + q * 2 + ry;
        for (int x0 = 0; x0 < 8; ++x0) {
            int xx = w * 8 + x0;
            float n[3][3];
            #pragma unroll
            for (int dy = -1; dy <= 1; ++dy) {
                #pragma unroll
                for (int dx = -1; dx <= 1; ++dx) {
                    int yy = y + dy, xc = xx + dx;
                    float v = 0.0f;
                    if (yy >= 0 && yy < 512 && xc >= 0 && xc < 512)
                        v = base[yy * 512 + xc];
                    n[dy + 1][dx + 1] = v;
                }
            }
            float gx = (n[0][2] - n[0][0]) + 2.0f * (n[1][2] - n[1][0]) + (n[2][2] - n[2][0]);
            float gy = (n[2][0] - n[0][0]) + 2.0f * (n[2][1] - n[0][1]) + (n[2][2] - n[0][2]);
            partial += sqrtf(gx * gx + gy * gy + 1e-6f);
        }
    }
    __shared__ float sred[256];
    sred[t] = partial;
    __syncthreads();
    if (t < 64) {
        float s = sred[t] + sred[t + 64] + sred[t + 128] + sred[t + 192];
        es[((size_t)b * 64 + hti) * 64 + t] = s * (1.0f / 64.0f);
    }
}

// ---------------- per-batch normalize: es -> f = (ec-1);  block 4: prep K0/K1 ----------------
__global__ __launch_bounds__(256) void k_coeff_prep(const float* __restrict__ es,
                                                    float* __restrict__ f,
                                                    const float* __restrict__ gain,
                                                    float* __restrict__ Kg) {
    int b = blockIdx.x;
    int t = threadIdx.x;
    if (b == 4) {
        // ---- prep: gain(6) -> K0[64] | K1[64] in Kg ----
        __shared__ float m0[40], m1[40];
        if (t < 40) {
            int ky = t / 5, kx = t % 5;
            int kyp = (ky < 8 - ky) ? ky : (8 - ky);
            float r = sqrtf((float)(kyp * kyp + kx * kx)) / (sqrtf(32.0f) + 1e-8f);
            r = fminf(fmaxf(r, 0.0f), 1.0f);
            float wv[6], wsum = 0.0f;
            #pragma unroll
            for (int i = 0; i < 6; ++i) {
                float c = 0.2f * (float)i;
                float v = fmaxf(1.0f - fabsf(r - c) * 5.0f, 0.0f);
                wv[i] = v; wsum += v;
            }
            float inv = 1.0f / (wsum + 1e-8f);
            float acc = 0.0f;
            #pragma unroll
            for (int i = 0; i < 6; ++i) acc += wv[i] * inv * gain[i];
            float mask = fmaxf(acc, 0.0f);
            m0[t] = mask;
            m1[t] = (r >= 0.6f) ? mask : 0.0f;
        }
        __syncthreads();
        if (t < 64) {
            int a = t >> 3, bb = t & 7;
            float s0 = 0.0f, s1 = 0.0f;
            for (int ky = 0; ky < 8; ++ky) {
                for (int kx = 0; kx < 8; ++kx) {
                    int kxh = (kx <= 4) ? kx : (8 - kx);
                    float c = C8[(ky * a + kx * bb) & 7];
                    s0 += m0[ky * 5 + kxh] * c;
                    s1 += m1[ky * 5 + kxh] * c;
                }
            }
            Kg[t] = s0 * (1.0f / 64.0f);
            Kg[64 + t] = s1 * (1.0f / 64.0f);
        }
        return;
    }
    const float* e = es + (size_t)b * 4096;
    float mn = 1e30f, mx = -1e30f;
    for (int i = t; i < 4096; i += 256) {
        float v = e[i];
        mn = fminf(mn, v); mx = fmaxf(mx, v);
    }
    #pragma unroll
    for (int off = 32; off > 0; off >>= 1) {
        mn = fminf(mn, __shfl_down(mn, off));
        mx = fmaxf(mx, __shfl_down(mx, off));
    }
    __shared__ float smn[4], smx[4];
    if ((t & 63) == 0) { smn[t >> 6] = mn; smx[t >> 6] = mx; }
    __syncthreads();
    mn = fminf(fminf(smn[0], smn[1]), fminf(smn[2], smn[3]));
    mx = fmaxf(fmaxf(smx[0], smx[1]), fmaxf(smx[2], smx[3]));
    float scale = 0.5f / (mx - mn + 1e-6f);
    for (int i = t; i < 4096; i += 256) {
        f[(size_t)b * 4096 + i] = (e[i] - mn) * scale;
    }
}

// ---------------- main: per-patch circular conv with K_eff = K0 + f*K1 ----------------
// 2 threads per patch: each computes 4 output rows (acc[32]), streams all
// 8 input rows a-outer (round-3 structure). Live set ~ 32 + 15 + 8 + addr
// ~= 70 VGPR -> 6+ waves/SIMD (round 6 post-mortem: 168 VGPR / 9.5%
// occupancy was the limiter, not load issue order).
__global__ __launch_bounds__(256) void k_main(const float* __restrict__ x,
                                              const float* __restrict__ Kg,
                                              const float* __restrict__ f,
                                              float* __restrict__ out) {
    // grid: 4096 = b(4) * hti(64) * cg(16); block 256: half(2) x cl(2) x w(64)
    int blk = blockIdx.x;
    int cg = blk & 15;
    int hti = (blk >> 4) & 63;
    int b = blk >> 10;
    int t = threadIdx.x;
    int half = t >> 7;          // 0: rows 0-3, 1: rows 4-7
    int idx = t & 127;
    int w = idx & 63;
    int c = cg * 2 + (idx >> 6);
    const int y0 = half * 4;

    // fc first: feeds the k[15] build that gates every FMA
    float fc = f[((size_t)b * 64 + hti) * 64 + w];

    size_t base = (((size_t)(b * 32 + c) * 512) + (size_t)hti * 8) * 512 + w * 8;
    const float* src = x + base;
    float* dst = out + base + (size_t)y0 * 512;

    // build the 15 unique kernel values (Kg reads are wave-uniform -> s_load)
    float k[15];
    #pragma unroll
    for (int a = 0; a <= 4; ++a) {
        #pragma unroll
        for (int d = a; d <= 4; ++d) {
            k[kid(a, d)] = fmaf(fc, Kg[64 + a * 8 + d], Kg[a * 8 + d]);
        }
    }

    float acc[32];
    #pragma unroll
    for (int i = 0; i < 32; ++i) acc[i] = 0.0f;

    #pragma unroll
    for (int a = 0; a < 8; ++a) {
        float4 p0 = *(const float4*)(src + a * 512);
        float4 p1 = *(const float4*)(src + a * 512 + 4);
        float pr[8] = {p0.x, p0.y, p0.z, p0.w, p1.x, p1.y, p1.z, p1.w};
        #pragma unroll
        for (int yy = 0; yy < 4; ++yy) {
            const int dy = (y0 + yy - a) & 7;
            #pragma unroll
            for (int bb = 0; bb < 8; ++bb) {
                const float pv = pr[bb];
                #pragma unroll
                for (int xx = 0; xx < 8; ++xx) {
                    acc[yy * 8 + xx] = fmaf(pv, k[kid(dy, (xx - bb) & 7)], acc[yy * 8 + xx]);
                }
            }
        }
    }

    #pragma unroll
    for (int yy = 0; yy < 4; ++yy) {
        float4 o0 = {acc[yy * 8 + 0], acc[yy * 8 + 1], acc[yy * 8 + 2], acc[yy * 8 + 3]};
        float4 o1 = {acc[yy * 8 + 4], acc[yy * 8 + 5], acc[yy * 8 + 6], acc[yy * 8 + 7]};
        *(float4*)(dst + yy * 512) = o0;
        *(float4*)(dst + yy * 512 + 4) = o1;
    }
}

extern "C" void kernel_launch(void* const* d_in, const int* in_sizes, int n_in,
                              void* d_out, int out_size, void* d_ws, size_t ws_size,
                              hipStream_t stream) {
    const float* x    = (const float*)d_in[0];   // (4,32,512,512)
    const float* gain = (const float*)d_in[1];   // (1,6)
    float* out = (float*)d_out;
    float* ws = (float*)d_ws;

    float* Kg = ws;                      // 128 floats: K0 | K1
    float* f  = ws + 128;                // 4*4096
    float* es = ws + 128 + 16384;        // 4*4096
    float* xm = ws + 128 + 2 * 16384;    // 4*512*512

    hipLaunchKernelGGL(k_mean, dim3(1024), dim3(256), 0, stream, x, xm);
    hipLaunchKernelGGL(k_edge, dim3(256), dim3(256), 0, stream, xm, es);
    hipLaunchKernelGGL(k_coeff_prep, dim3(5), dim3(256), 0, stream, es, f, gain, Kg);
    hipLaunchKernelGGL(k_main, dim3(4096), dim3(256), 0, stream, x, Kg, f, out);
}

// Round 8
// 105.210 us; speedup vs baseline: 2.0331x; 2.0331x over previous
//
#include <hip/hip_runtime.h>
#include <hip/hip_bf16.h>

// cos(2*pi*t/8), t = 0..7
__device__ const float C8[8] = {
    1.0f, 0.70710678118654752f, 0.0f, -0.70710678118654752f,
   -1.0f, -0.70710678118654752f, 0.0f, 0.70710678118654752f
};

// Unique-id map for the 8x8 circular-conv kernel, which is even in both axes
// and symmetric under (dy,dx) swap: 15 unique values for d1<=d2 in [0,4].
__host__ __device__ constexpr int kid(int dy, int dx) {
    int a = (dy < 8 - dy) ? dy : 8 - dy;
    int b = (dx < 8 - dx) ? dx : 8 - dx;
    int lo = a < b ? a : b, hi = a < b ? b : a;
    return lo * 5 - lo * (lo - 1) / 2 + (hi - lo);
}

// ---------------- channel mean: x(4,32,512,512) -> xm(4,512,512) ----------------
__global__ __launch_bounds__(256) void k_mean(const float* __restrict__ x,
                                              float* __restrict__ xm) {
    int idx = blockIdx.x * 256 + threadIdx.x;   // float4 index, 262144 total
    int b = idx >> 16;                          // 65536 float4 per batch plane
    int rem = idx & 65535;
    const float4* xp = (const float4*)x + (size_t)b * 32 * 65536 + rem;
    float4 acc = {0.f, 0.f, 0.f, 0.f};
    #pragma unroll 8
    for (int c = 0; c < 32; ++c) {
        float4 v = xp[(size_t)c * 65536];
        acc.x += v.x; acc.y += v.y; acc.z += v.z; acc.w += v.w;
    }
    const float s = 1.0f / 32.0f;
    acc.x *= s; acc.y *= s; acc.z *= s; acc.w *= s;
    ((float4*)xm)[idx] = acc;
}

// ---------------- edge strength per patch: xm -> es(4,64,64) ----------------
__global__ __launch_bounds__(256) void k_edge(const float* __restrict__ xm,
                                              float* __restrict__ es) {
    int b = blockIdx.x >> 6;
    int hti = blockIdx.x & 63;
    int t = threadIdx.x;
    int w = t & 63;     // patch column
    int q = t >> 6;     // quarter: rows q*2, q*2+1 of the patch
    const float* base = xm + (size_t)b * 512 * 512;
    float partial = 0.0f;
    for (int ry = 0; ry < 2; ++ry) {
        int y = hti * 8 + q * 2 + ry;
        for (int x0 = 0; x0 < 8; ++x0) {
            int xx = w * 8 + x0;
            float n[3][3];
            #pragma unroll
            for (int dy = -1; dy <= 1; ++dy) {
                #pragma unroll
                for (int dx = -1; dx <= 1; ++dx) {
                    int yy = y + dy, xc = xx + dx;
                    float v = 0.0f;
                    if (yy >= 0 && yy < 512 && xc >= 0 && xc < 512)
                        v = base[yy * 512 + xc];
                    n[dy + 1][dx + 1] = v;
                }
            }
            float gx = (n[0][2] - n[0][0]) + 2.0f * (n[1][2] - n[1][0]) + (n[2][2] - n[2][0]);
            float gy = (n[2][0] - n[0][0]) + 2.0f * (n[2][1] - n[0][1]) + (n[2][2] - n[0][2]);
            partial += sqrtf(gx * gx + gy * gy + 1e-6f);
        }
    }
    __shared__ float sred[256];
    sred[t] = partial;
    __syncthreads();
    if (t < 64) {
        float s = sred[t] + sred[t + 64] + sred[t + 128] + sred[t + 192];
        es[((size_t)b * 64 + hti) * 64 + t] = s * (1.0f / 64.0f);
    }
}

// ---------------- per-batch normalize: es -> f = (ec-1);  block 4: prep K0/K1 ----------------
__global__ __launch_bounds__(256) void k_coeff_prep(const float* __restrict__ es,
                                                    float* __restrict__ f,
                                                    const float* __restrict__ gain,
                                                    float* __restrict__ Kg) {
    int b = blockIdx.x;
    int t = threadIdx.x;
    if (b == 4) {
        // ---- prep: gain(6) -> K0[64] | K1[64] in Kg ----
        __shared__ float m0[40], m1[40];
        if (t < 40) {
            int ky = t / 5, kx = t % 5;
            int kyp = (ky < 8 - ky) ? ky : (8 - ky);
            float r = sqrtf((float)(kyp * kyp + kx * kx)) / (sqrtf(32.0f) + 1e-8f);
            r = fminf(fmaxf(r, 0.0f), 1.0f);
            float wv[6], wsum = 0.0f;
            #pragma unroll
            for (int i = 0; i < 6; ++i) {
                float c = 0.2f * (float)i;
                float v = fmaxf(1.0f - fabsf(r - c) * 5.0f, 0.0f);
                wv[i] = v; wsum += v;
            }
            float inv = 1.0f / (wsum + 1e-8f);
            float acc = 0.0f;
            #pragma unroll
            for (int i = 0; i < 6; ++i) acc += wv[i] * inv * gain[i];
            float mask = fmaxf(acc, 0.0f);
            m0[t] = mask;
            m1[t] = (r >= 0.6f) ? mask : 0.0f;
        }
        __syncthreads();
        if (t < 64) {
            int a = t >> 3, bb = t & 7;
            float s0 = 0.0f, s1 = 0.0f;
            for (int ky = 0; ky < 8; ++ky) {
                for (int kx = 0; kx < 8; ++kx) {
                    int kxh = (kx <= 4) ? kx : (8 - kx);
                    float c = C8[(ky * a + kx * bb) & 7];
                    s0 += m0[ky * 5 + kxh] * c;
                    s1 += m1[ky * 5 + kxh] * c;
                }
            }
            Kg[t] = s0 * (1.0f / 64.0f);
            Kg[64 + t] = s1 * (1.0f / 64.0f);
        }
        return;
    }
    const float* e = es + (size_t)b * 4096;
    float mn = 1e30f, mx = -1e30f;
    for (int i = t; i < 4096; i += 256) {
        float v = e[i];
        mn = fminf(mn, v); mx = fmaxf(mx, v);
    }
    #pragma unroll
    for (int off = 32; off > 0; off >>= 1) {
        mn = fminf(mn, __shfl_down(mn, off));
        mx = fmaxf(mx, __shfl_down(mx, off));
    }
    __shared__ float smn[4], smx[4];
    if ((t & 63) == 0) { smn[t >> 6] = mn; smx[t >> 6] = mx; }
    __syncthreads();
    mn = fminf(fminf(smn[0], smn[1]), fminf(smn[2], smn[3]));
    mx = fmaxf(fmaxf(smx[0], smx[1]), fmaxf(smx[2], smx[3]));
    float scale = 0.5f / (mx - mn + 1e-6f);
    for (int i = t; i < 4096; i += 256) {
        f[(size_t)b * 4096 + i] = (e[i] - mn) * scale;
    }
}

// ---------------- main: per-patch circular conv with K_eff = K0 + f*K1 ----------------
// 2 threads per patch, 4 output rows each (acc[32]). Modular rotation: loop
// j (compile-time), process input row a=(j+y0)&7 -> dy=(yy-j)&7 is fully
// compile-time, so all k[]/pr[] indices are constants (round-7 post-mortem:
// runtime y0 in the k[] index forced non-register lowering). Only the row
// byte offset is runtime-uniform. Live set ~ 32+8+15+addr ~= 70 VGPR.
__global__ __launch_bounds__(256) void k_main(const float* __restrict__ x,
                                              const float* __restrict__ Kg,
                                              const float* __restrict__ f,
                                              float* __restrict__ out) {
    // grid: 4096 = b(4) * hti(64) * cg(16); block 256: half(2) x cl(2) x w(64)
    int blk = blockIdx.x;
    int cg = blk & 15;
    int hti = (blk >> 4) & 63;
    int b = blk >> 10;
    int t = threadIdx.x;
    int half = t >> 7;          // wave-uniform: 0 -> rows 0-3, 1 -> rows 4-7
    int idx = t & 127;
    int w = idx & 63;
    int c = cg * 2 + (idx >> 6);
    const int y0 = half * 4;

    // fc first: feeds the k[15] build that gates every FMA
    float fc = f[((size_t)b * 64 + hti) * 64 + w];

    size_t base = (((size_t)(b * 32 + c) * 512) + (size_t)hti * 8) * 512 + w * 8;
    const float* src = x + base;
    float* dst = out + base + (size_t)y0 * 512;

    // build the 15 unique kernel values (Kg reads are wave-uniform -> s_load)
    float k[15];
    #pragma unroll
    for (int a = 0; a <= 4; ++a) {
        #pragma unroll
        for (int d = a; d <= 4; ++d) {
            k[kid(a, d)] = fmaf(fc, Kg[64 + a * 8 + d], Kg[a * 8 + d]);
        }
    }

    float acc[32];
    #pragma unroll
    for (int i = 0; i < 32; ++i) acc[i] = 0.0f;

    #pragma unroll
    for (int j = 0; j < 8; ++j) {
        const int a = (j + y0) & 7;           // runtime-uniform row index
        const float* row = src + a * 512;     // address arithmetic only
        float4 p0 = *(const float4*)(row);
        float4 p1 = *(const float4*)(row + 4);
        float pr[8] = {p0.x, p0.y, p0.z, p0.w, p1.x, p1.y, p1.z, p1.w};
        #pragma unroll
        for (int yy = 0; yy < 4; ++yy) {
            const int dy = (yy - j) & 7;      // compile-time
            #pragma unroll
            for (int bb = 0; bb < 8; ++bb) {
                const float pv = pr[bb];
                #pragma unroll
                for (int xx = 0; xx < 8; ++xx) {
                    acc[yy * 8 + xx] = fmaf(pv, k[kid(dy, (xx - bb) & 7)], acc[yy * 8 + xx]);
                }
            }
        }
    }

    #pragma unroll
    for (int yy = 0; yy < 4; ++yy) {
        float4 o0 = {acc[yy * 8 + 0], acc[yy * 8 + 1], acc[yy * 8 + 2], acc[yy * 8 + 3]};
        float4 o1 = {acc[yy * 8 + 4], acc[yy * 8 + 5], acc[yy * 8 + 6], acc[yy * 8 + 7]};
        *(float4*)(dst + yy * 512) = o0;
        *(float4*)(dst + yy * 512 + 4) = o1;
    }
}

extern "C" void kernel_launch(void* const* d_in, const int* in_sizes, int n_in,
                              void* d_out, int out_size, void* d_ws, size_t ws_size,
                              hipStream_t stream) {
    const float* x    = (const float*)d_in[0];   // (4,32,512,512)
    const float* gain = (const float*)d_in[1];   // (1,6)
    float* out = (float*)d_out;
    float* ws = (float*)d_ws;

    float* Kg = ws;                      // 128 floats: K0 | K1
    float* f  = ws + 128;                // 4*4096
    float* es = ws + 128 + 16384;        // 4*4096
    float* xm = ws + 128 + 2 * 16384;    // 4*512*512

    hipLaunchKernelGGL(k_mean, dim3(1024), dim3(256), 0, stream, x, xm);
    hipLaunchKernelGGL(k_edge, dim3(256), dim3(256), 0, stream, xm, es);
    hipLaunchKernelGGL(k_coeff_prep, dim3(5), dim3(256), 0, stream, es, f, gain, Kg);
    hipLaunchKernelGGL(k_main, dim3(4096), dim3(256), 0, stream, x, Kg, f, out);
}